// Round 8
// baseline (1426.728 us; speedup 1.0000x reference)
//
#include <hip/hip_runtime.h>

// Problem constants
constexpr int TT = 512;    // sequence length
constexpr int BB = 2048;   // batch
constexpr int HH = 11;     // hidden size
constexpr int GG = 44;     // 4*HH gates
constexpr int NL = 5;      // layers

typedef float v2f __attribute__((ext_vector_type(2)));

// quad_perm broadcast of lane q within each quad (ctrl = q * 0x55)
__device__ __forceinline__ float dpp_q0(float v) {
    return __int_as_float(__builtin_amdgcn_mov_dpp(__float_as_int(v), 0x00, 0xF, 0xF, false));
}
__device__ __forceinline__ float dpp_q1(float v) {
    return __int_as_float(__builtin_amdgcn_mov_dpp(__float_as_int(v), 0x55, 0xF, 0xF, false));
}
__device__ __forceinline__ float dpp_q3(float v) {
    return __int_as_float(__builtin_amdgcn_mov_dpp(__float_as_int(v), 0xFF, 0xF, 0xF, false));
}
// quad_perm [2,3,0,1]: lane q gets lane q^2 of its quad (ctrl 0x4E)
__device__ __forceinline__ float dpp_qswap2(float v) {
    return __int_as_float(__builtin_amdgcn_mov_dpp(__float_as_int(v), 0x4E, 0xF, 0xF, false));
}

// inp[b][t] = sum_k x[b][0][k][t]
__global__ void reduce_x(const float* __restrict__ x, float* __restrict__ inp) {
    int t = blockIdx.x * 256 + threadIdx.x;   // grid.x = 2 -> t in [0,512)
    int b = blockIdx.y;
    const float* p = x + (size_t)b * 32 * TT + t;
    float s = 0.f;
#pragma unroll
    for (int k = 0; k < 32; k++) s += p[k * TT];
    inp[(size_t)b * TT + t] = s;
}

// One wave per (batch, dir). Lane = 4*u + q, u = hidden unit, q = gate
// (0:i 1:f 2:g 3:o). Weight row in W is q*HH + u. Lanes u >= 11 run with
// zero weights (benign), stores masked.
//
// x staging: per-wave-private LDS chunks (CH rows), double-buffered, no
// barriers (regions wave-private). Chunk c+1 global loads issue at the
// START of chunk c (vmcnt-covered by 32 steps), ds_written at the end.
//
// h transport via LDS (replaces 11 v_readlane + pairing movs): h is
// quad-uniform, so every lane ds_writes its h to shh[lane]; the 6 hp
// pairs {shh[8k], shh[8k+4]} = {h_2k, h_2k+1} each compile to one
// broadcast ds_read2_b32 -> v2f operand for v_pk_fma_f32. Slot 44 junk
// (inactive lane, finite) is killed by the zero weight whh2[5].y.
//
// Scaled domain: weights/bias pre-multiplied by -log2e (i,f,o) or
// -2*log2e (g); c kept as c' = -2*log2e*c_true so both exp2 inputs need
// no per-step multiply.
template <int IND>
__global__ __launch_bounds__(256, 4)   // 4 waves/EU -> 128-VGPR budget
void lstm_layer(
    const float* __restrict__ xin,   // [chunk][TT][IND]
    float* __restrict__ out,         // [chunk][TT][22]
    const float* __restrict__ Wih,   // [2][GG][IND]
    const float* __restrict__ Whh,   // [2][GG][HH]
    const float* __restrict__ bih,   // [2][GG]
    const float* __restrict__ bhh)   // [2][GG]
{
    constexpr int NP   = (IND > 1) ? IND / 2 : 1;  // v2f pairs per x row
    constexpr int CH   = (IND == 1) ? 64 : 32;     // rows per staged chunk
    constexpr int NCH  = TT / CH;                  // chunks per sequence
    constexpr int NLD  = (CH * IND) / 64;          // dwords/lane per chunk
    constexpr int PERW = 64 + 2 * CH * IND;        // h slots + 2 x buffers

    __shared__ float smem[4 * PERW];

    const float L2E   = 1.4426950408889634f;
    const float NL2E  = -L2E;
    const float N2L2E = -2.f * L2E;

    int tid  = threadIdx.x;
    int lane = tid & 63;
    int wid  = tid >> 6;
    int u = lane >> 2;
    int q = lane & 3;
    bool active = (u < HH);
    int grow = q * HH + u;

    int seq = __builtin_amdgcn_readfirstlane((int)blockIdx.x * 4 + wid);
    int b = seq >> 1;
    int d = seq & 1;

    float esc    = (q == 2) ? N2L2E : NL2E;
    float ascale = (q == 2) ? 2.f * N2L2E : 1.f;
    float aoff   = (q == 2) ? -N2L2E : 0.f;

    v2f   wih2[NP];
    float wih0 = 0.f;
    v2f   whh2[6];          // paired Whh row, last slot y-padded with 0
    v2f   bias2;
    if (active) {
        const float* wi = Wih + (size_t)(d * GG + grow) * IND;
        if constexpr (IND == 1) {
            wih0 = wi[0] * esc;
        } else {
#pragma unroll
            for (int p = 0; p < NP; p++) wih2[p] = ((const v2f*)wi)[p] * esc;
        }
        const float* wh = Whh + (size_t)(d * GG + grow) * HH;
#pragma unroll
        for (int k = 0; k < 5; k++)
            whh2[k] = (v2f){wh[2 * k] * esc, wh[2 * k + 1] * esc};
        whh2[5] = (v2f){wh[10] * esc, 0.f};
        float bv = (bih[d * GG + grow] + bhh[d * GG + grow]) * esc;
        bias2 = (v2f){bv, 0.f};
    } else {
        if constexpr (IND != 1) {
#pragma unroll
            for (int p = 0; p < NP; p++) wih2[p] = (v2f){0.f, 0.f};
        }
#pragma unroll
        for (int k = 0; k < 6; k++) whh2[k] = (v2f){0.f, 0.f};
        bias2 = (v2f){0.f, 0.f};
    }

    // h pairs (consumed by pk_fma); step 0 uses these zeros
    v2f hp[6];
#pragma unroll
    for (int k = 0; k < 6; k++) hp[k] = (v2f){0.f, 0.f};
    float c = 0.f;  // scaled domain c' = -2*log2e * c_true

    const int ostep = d ? -22 : 22;
    float* op = out + (size_t)b * TT * 22 + (size_t)(d ? (TT - 1) * 22 : 0)
                    + d * HH + u;
    const bool doStore = (q == 0) && active;

    // ---- LDS bases ----
    float* shh = smem + wid * PERW;   // 64 h slots
    float* xls = shh + 64;            // 2 x chunk buffers

    // ---- x chunk staging setup ----
    const float* gbase = xin + (size_t)b * TT * IND
                             + (size_t)(d ? (TT - CH) * IND : 0);
    const int gstep = d ? -(CH * IND) : (CH * IND);     // chunk-to-chunk
    const int lstep = d ? -IND : IND;                   // row-to-row in LDS

    {   // stage chunk 0 (regs -> LDS)
        float p0[NLD];
#pragma unroll
        for (int k = 0; k < NLD; k++) p0[k] = gbase[k * 64 + lane];
#pragma unroll
        for (int k = 0; k < NLD; k++) xls[k * 64 + lane] = p0[k];
    }
    int buf = 0;
    float* swc = xls;
    const float* lrow = swc + (d ? (CH - 1) * IND : 0); // first consumed row

    // row register ping-pong (one row of lookahead over LDS)
    v2f   xA[NP], xB[NP];
    float xAs = 0.f, xBs = 0.f;
    if constexpr (IND == 1) {
        xAs = lrow[0];
    } else {
#pragma unroll
        for (int p = 0; p < NP; p++) xA[p] = ((const v2f*)lrow)[p];
    }

    const float* gnext = gbase + gstep;                 // chunk 1 source

#define LSTM_STEP(XC, XN, DOPF)                                               \
    do {                                                                      \
        v2f accA, accB;                                                       \
        float pre;                                                            \
        if constexpr (IND == 1) {                                             \
            accA = __builtin_elementwise_fma(hp[0], whh2[0], bias2);          \
            accB = hp[1] * whh2[1];                                           \
            _Pragma("unroll")                                                 \
            for (int k = 2; k < 6; k++) {                                     \
                if (k & 1) accB = __builtin_elementwise_fma(hp[k], whh2[k], accB);\
                else       accA = __builtin_elementwise_fma(hp[k], whh2[k], accA);\
            }                                                                 \
            v2f s = accA + accB;                                              \
            pre = fmaf(XC##s, wih0, s.x + s.y);                               \
            if (DOPF) { lrow += lstep; XN##s = lrow[0]; }                     \
        } else {                                                              \
            /* x-dot first: hides the hp ds_read2 latency from prev step */   \
            accA = __builtin_elementwise_fma(XC[0], wih2[0], bias2);          \
            accB = XC[1] * wih2[1];                                           \
            _Pragma("unroll")                                                 \
            for (int p = 2; p < NP; p++) {                                    \
                if (p & 1) accB = __builtin_elementwise_fma(XC[p], wih2[p], accB);\
                else       accA = __builtin_elementwise_fma(XC[p], wih2[p], accA);\
            }                                                                 \
            if (DOPF) {  /* prefetch next consumed row from LDS */            \
                lrow += lstep;                                                \
                _Pragma("unroll")                                             \
                for (int p = 0; p < NP; p++) XN[p] = ((const v2f*)lrow)[p];   \
            }                                                                 \
            /* h-dot last */                                                  \
            _Pragma("unroll")                                                 \
            for (int k = 0; k < 6; k++) {                                     \
                if (k & 1) accB = __builtin_elementwise_fma(hp[k], whh2[k], accB);\
                else       accA = __builtin_elementwise_fma(hp[k], whh2[k], accA);\
            }                                                                 \
            v2f s = accA + accB;                                              \
            pre = s.x + s.y;                                                  \
        }                                                                     \
        float e   = __builtin_amdgcn_exp2f(pre);                              \
        float act = fmaf(ascale, __builtin_amdgcn_rcpf(1.f + e), aoff);       \
        float ig  = act * dpp_qswap2(act);   /* q0 lane: i*g' */              \
        float igb = dpp_q0(ig);                                               \
        float fv  = dpp_q1(act);                                              \
        float ov  = dpp_q3(act);                                              \
        c = fmaf(fv, c, igb);                                                 \
        float e2 = __builtin_amdgcn_exp2f(c);                                 \
        float th = fmaf(2.f, __builtin_amdgcn_rcpf(1.f + e2), -1.f);          \
        float h  = ov * th;                  /* quad-uniform */               \
        if (doStore) *op = h;                                                 \
        op += ostep;                                                          \
        /* h transport: write own h; read broadcast pairs for next step */    \
        shh[lane] = h;                                                        \
        _Pragma("unroll")                                                     \
        for (int k = 0; k < 6; k++)                                           \
            hp[k] = (v2f){shh[8 * k], shh[8 * k + 4]};                        \
    } while (0)

    for (int ch = 0; ch < NCH; ch++) {
        const bool last = (ch + 1 == NCH);
        float pf[NLD];
        if (!last) {   // issue next-chunk loads now; vmcnt-covered by CH steps
#pragma unroll
            for (int k = 0; k < NLD; k++) pf[k] = gnext[k * 64 + lane];
        }
        // steps 0 .. CH-3 (pairs), each prefetches its successor row
        for (int sl = 0; sl < CH - 2; sl += 2) {
            LSTM_STEP(xA, xB, true);
            LSTM_STEP(xB, xA, true);
        }
        LSTM_STEP(xA, xB, true);     // step CH-2 (prefetches row CH-1)
        LSTM_STEP(xB, xA, false);    // step CH-1 (no in-chunk prefetch)
        if (!last) {
            float* swn = xls + ((buf ^ 1) ? CH * IND : 0);
#pragma unroll
            for (int k = 0; k < NLD; k++) swn[k * 64 + lane] = pf[k];
            buf ^= 1;
            swc = swn;
            lrow = swc + (d ? (CH - 1) * IND : 0);
            if constexpr (IND == 1) {
                xAs = lrow[0];
            } else {
#pragma unroll
                for (int p = 0; p < NP; p++) xA[p] = ((const v2f*)lrow)[p];
            }
            gnext += gstep;
        }
    }
#undef LSTM_STEP
}

extern "C" void kernel_launch(void* const* d_in, const int* in_sizes, int n_in,
                              void* d_out, int out_size, void* d_ws, size_t ws_size,
                              hipStream_t stream) {
    const float* x        = (const float*)d_in[0]; // [2048,1,32,512]
    const float* W_ih0    = (const float*)d_in[1]; // [2,44,1]
    const float* W_ih_rest= (const float*)d_in[2]; // [4,2,44,22]
    const float* W_hh     = (const float*)d_in[3]; // [5,2,44,11]
    const float* b_ih     = (const float*)d_in[4]; // [5,2,44]
    const float* b_hh     = (const float*)d_in[5]; // [5,2,44]
    float* out = (float*)d_out;                    // [2048,512,22]

    // Workspace: one ping buffer of chunk*TT*22 floats; largest pow2 chunk
    // that fits ws_size. The x-reduction is staged in the same buffer (its
    // lifetime ends when layer 1 overwrites it). d_out is the pong buffer.
    const size_t perB = (size_t)TT * 22 * sizeof(float);
    int chunk = BB;
    while (chunk > 2 && (size_t)chunk * perB > ws_size) chunk >>= 1;
    float* wsbuf = (float*)d_ws;

    for (int c0 = 0; c0 < BB; c0 += chunk) {
        const float* xc   = x + (size_t)c0 * 32 * TT;
        float*       outc = out + (size_t)c0 * TT * 22;
        const int nblk = (chunk * 2) / 4;  // 4 sequences (waves) per block

        reduce_x<<<dim3(2, chunk), 256, 0, stream>>>(xc, wsbuf);

        lstm_layer<1><<<nblk, 256, 0, stream>>>(wsbuf, outc, W_ih0, W_hh, b_ih, b_hh);

        for (int l = 1; l < NL; l++) {
            const float* src = (l & 1) ? outc : wsbuf;
            float*       dst = (l & 1) ? wsbuf : outc;
            lstm_layer<22><<<nblk, 256, 0, stream>>>(
                src, dst,
                W_ih_rest + (size_t)(l - 1) * 2 * GG * 22,
                W_hh + (size_t)l * 2 * GG * HH,
                b_ih + (size_t)l * 2 * GG,
                b_hh + (size_t)l * 2 * GG);
        }
    }
}

// Round 9
// 1229.863 us; speedup vs baseline: 1.1601x; 1.1601x over previous
//
#include <hip/hip_runtime.h>

// Problem constants
constexpr int TT = 512;    // sequence length
constexpr int BB = 2048;   // batch
constexpr int HH = 11;     // hidden size
constexpr int GG = 44;     // 4*HH gates
constexpr int NL = 5;      // layers

typedef float v2f __attribute__((ext_vector_type(2)));
typedef float v4f __attribute__((ext_vector_type(4)));

// quad_perm broadcast of lane q within each quad (ctrl = q * 0x55)
__device__ __forceinline__ float dpp_q0(float v) {
    return __int_as_float(__builtin_amdgcn_mov_dpp(__float_as_int(v), 0x00, 0xF, 0xF, false));
}
__device__ __forceinline__ float dpp_q1(float v) {
    return __int_as_float(__builtin_amdgcn_mov_dpp(__float_as_int(v), 0x55, 0xF, 0xF, false));
}
__device__ __forceinline__ float dpp_q3(float v) {
    return __int_as_float(__builtin_amdgcn_mov_dpp(__float_as_int(v), 0xFF, 0xF, 0xF, false));
}
// quad_perm [2,3,0,1]: lane q gets lane q^2 of its quad (ctrl 0x4E)
__device__ __forceinline__ float dpp_qswap2(float v) {
    return __int_as_float(__builtin_amdgcn_mov_dpp(__float_as_int(v), 0x4E, 0xF, 0xF, false));
}

// inp[b][t] = sum_k x[b][0][k][t]
__global__ void reduce_x(const float* __restrict__ x, float* __restrict__ inp) {
    int t = blockIdx.x * 256 + threadIdx.x;   // grid.x = 2 -> t in [0,512)
    int b = blockIdx.y;
    const float* p = x + (size_t)b * 32 * TT + t;
    float s = 0.f;
#pragma unroll
    for (int k = 0; k < 32; k++) s += p[k * TT];
    inp[(size_t)b * TT + t] = s;
}

// One wave per (batch, dir). Lane = 4*u + q, u = hidden unit, q = gate
// (0:i 1:f 2:g 3:o). Weight row in W is q*HH + u. Lanes u >= 11 run with
// zero weights (benign, h=0 exactly), stores masked.
//
// x staging: per-wave-private LDS chunks (CH rows padded to RS floats so
// every row base is 16B-aligned -> 5x ds_read_b128 + 1x ds_read_b64 per
// row), double-buffered, no barriers. The staging write permutation
// wdw[] also folds the d=1 row flip, so consumption is ascending (+RS)
// for both directions. Chunk c+1 global loads issue at the START of
// chunk c (vmcnt-covered by CH steps), ds_written at the end.
//
// h broadcast: inline-asm 12x v_readlane into s20..s31 + 6x v_pk_fma_f32
// consuming the SGPR pairs directly (one 64-bit scalar operand per VALU
// op) -- removes the ~12 v_mov pairing instructions the compiler emits
// for the generic-IR version. Pad slot (lane 44) h is exactly 0 and is
// killed by the zero weight whh2[5].y.
//
// Scaled domain: weights/bias pre-multiplied by -log2e (i,f,o) or
// -2*log2e (g); c kept as c' = -2*log2e*c_true so both exp2 inputs need
// no per-step multiply.
template <int IND>
__global__ __launch_bounds__(256, 4)   // 4 waves/EU -> 128-VGPR budget
void lstm_layer(
    const float* __restrict__ xin,   // [chunk][TT][IND]
    float* __restrict__ out,         // [chunk][TT][22]
    const float* __restrict__ Wih,   // [2][GG][IND]
    const float* __restrict__ Whh,   // [2][GG][HH]
    const float* __restrict__ bih,   // [2][GG]
    const float* __restrict__ bhh)   // [2][GG]
{
    constexpr int NP    = (IND > 1) ? IND / 2 : 1;  // v2f pairs per x row
    constexpr int CH    = (IND == 1) ? 64 : 32;     // rows per staged chunk
    constexpr int NCH   = TT / CH;                  // chunks per sequence
    constexpr int NLD   = (CH * IND) / 64;          // dwords/lane per chunk
    constexpr int RS    = (IND == 1) ? 1 : 24;      // padded LDS row stride
    constexpr int BUFSZ = CH * RS;

    __shared__ __align__(16) float smem[4 * 2 * BUFSZ];

    const float L2E   = 1.4426950408889634f;
    const float NL2E  = -L2E;
    const float N2L2E = -2.f * L2E;

    int tid  = threadIdx.x;
    int lane = tid & 63;
    int wid  = tid >> 6;
    int u = lane >> 2;
    int q = lane & 3;
    bool active = (u < HH);
    int grow = q * HH + u;

    int seq = __builtin_amdgcn_readfirstlane((int)blockIdx.x * 4 + wid);
    int b = seq >> 1;
    int d = seq & 1;

    float esc    = (q == 2) ? N2L2E : NL2E;
    float ascale = (q == 2) ? 2.f * N2L2E : 1.f;
    float aoff   = (q == 2) ? -N2L2E : 0.f;

    v2f   wih2[NP];
    float wih0 = 0.f;
    v2f   whh2[6];          // paired Whh row, last slot y-padded with 0
    v2f   bias2;
    if (active) {
        const float* wi = Wih + (size_t)(d * GG + grow) * IND;
        if constexpr (IND == 1) {
            wih0 = wi[0] * esc;
        } else {
#pragma unroll
            for (int p = 0; p < NP; p++) wih2[p] = ((const v2f*)wi)[p] * esc;
        }
        const float* wh = Whh + (size_t)(d * GG + grow) * HH;
#pragma unroll
        for (int k = 0; k < 5; k++)
            whh2[k] = (v2f){wh[2 * k] * esc, wh[2 * k + 1] * esc};
        whh2[5] = (v2f){wh[10] * esc, 0.f};
        float bv = (bih[d * GG + grow] + bhh[d * GG + grow]) * esc;
        bias2 = (v2f){bv, 0.f};
    } else {
        if constexpr (IND != 1) {
#pragma unroll
            for (int p = 0; p < NP; p++) wih2[p] = (v2f){0.f, 0.f};
        }
#pragma unroll
        for (int k = 0; k < 6; k++) whh2[k] = (v2f){0.f, 0.f};
        bias2 = (v2f){0.f, 0.f};
    }

    float hprev = 0.f;   // quad-uniform h of previous step (readlane source)
    float c = 0.f;       // scaled domain c' = -2*log2e * c_true

    const int ostep = d ? -22 : 22;
    float* op = out + (size_t)b * TT * 22 + (size_t)(d ? (TT - 1) * 22 : 0)
                    + d * HH + u;
    const bool doStore = (q == 0) && active;

    // ---- LDS base (wave-private, 2 buffers) ----
    float* xls = smem + wid * (2 * BUFSZ);

    // ---- global staging ----
    const float* gbase = xin + (size_t)b * TT * IND
                             + (size_t)(d ? (TT - CH) * IND : 0);
    const int gstep = d ? -(CH * IND) : (CH * IND);

    // staging write-dword map into padded rows; d=1 flips row order so
    // consumption is always ascending
    int wdw[NLD];
#pragma unroll
    for (int k = 0; k < NLD; k++) {
        int p = k * 64 + lane;
        int row = p / IND;
        int col = p - row * IND;
        int r2 = d ? (CH - 1 - row) : row;
        wdw[k] = r2 * RS + col;
    }

    {   // stage chunk 0
        float p0[NLD];
#pragma unroll
        for (int k = 0; k < NLD; k++) p0[k] = gbase[k * 64 + lane];
#pragma unroll
        for (int k = 0; k < NLD; k++) xls[wdw[k]] = p0[k];
    }
    int buf = 0;
    const float* lrow = xls;          // consumed row (ascending, both dirs)
    const float* gnext = gbase + gstep;

    // row register ping-pong (one row of lookahead over LDS)
    v2f   xA[NP], xB[NP];
    float xAs = 0.f, xBs = 0.f;

#define LOAD_ROW(DST, PTR)                                                    \
    do {                                                                      \
        if constexpr (IND == 1) {                                             \
            DST##s = (PTR)[0];                                                \
        } else {                                                              \
            _Pragma("unroll")                                                 \
            for (int i4 = 0; i4 < 5; i4++) {                                  \
                v4f t4 = ((const v4f*)(PTR))[i4];                             \
                DST[2 * i4]     = (v2f){t4.x, t4.y};                          \
                DST[2 * i4 + 1] = (v2f){t4.z, t4.w};                          \
            }                                                                 \
            DST[10] = ((const v2f*)(PTR))[10];                                \
        }                                                                     \
    } while (0)

    LOAD_ROW(xA, lrow);   // row 0

#define LSTM_STEP(XC, XN, DOPF)                                               \
    do {                                                                      \
        v2f accA, accB;                                                       \
        if constexpr (IND == 1) {                                             \
            accA = bias2;                                                     \
            accB = (v2f){0.f, 0.f};                                           \
        } else {                                                              \
            accA = __builtin_elementwise_fma(XC[0], wih2[0], bias2);          \
            accB = XC[1] * wih2[1];                                           \
            _Pragma("unroll")                                                 \
            for (int p = 2; p < NP; p++) {                                    \
                if (p & 1) accB = __builtin_elementwise_fma(XC[p], wih2[p], accB);\
                else       accA = __builtin_elementwise_fma(XC[p], wih2[p], accA);\
            }                                                                 \
        }                                                                     \
        if (DOPF) { lrow += RS; LOAD_ROW(XN, lrow); }                         \
        /* h-dot: readlane pairs -> SGPR pairs -> pk_fma scalar operand */    \
        asm volatile(                                                         \
            "v_readlane_b32 s20, %2, 0\n\t"                                   \
            "v_readlane_b32 s21, %2, 4\n\t"                                   \
            "v_readlane_b32 s22, %2, 8\n\t"                                   \
            "v_readlane_b32 s23, %2, 12\n\t"                                  \
            "v_readlane_b32 s24, %2, 16\n\t"                                  \
            "v_readlane_b32 s25, %2, 20\n\t"                                  \
            "v_readlane_b32 s26, %2, 24\n\t"                                  \
            "v_readlane_b32 s27, %2, 28\n\t"                                  \
            "v_readlane_b32 s28, %2, 32\n\t"                                  \
            "v_readlane_b32 s29, %2, 36\n\t"                                  \
            "v_readlane_b32 s30, %2, 40\n\t"                                  \
            "v_readlane_b32 s31, %2, 44\n\t"                                  \
            "v_pk_fma_f32 %0, s[20:21], %3, %0\n\t"                           \
            "v_pk_fma_f32 %1, s[22:23], %4, %1\n\t"                           \
            "v_pk_fma_f32 %0, s[24:25], %5, %0\n\t"                           \
            "v_pk_fma_f32 %1, s[26:27], %6, %1\n\t"                           \
            "v_pk_fma_f32 %0, s[28:29], %7, %0\n\t"                           \
            "v_pk_fma_f32 %1, s[30:31], %8, %1"                               \
            : "+v"(accA), "+v"(accB)                                          \
            : "v"(hprev), "v"(whh2[0]), "v"(whh2[1]), "v"(whh2[2]),           \
              "v"(whh2[3]), "v"(whh2[4]), "v"(whh2[5])                        \
            : "s20","s21","s22","s23","s24","s25","s26","s27",                \
              "s28","s29","s30","s31");                                       \
        v2f s2 = accA + accB;                                                 \
        float pre = s2.x + s2.y;                                              \
        if constexpr (IND == 1) pre = fmaf(XC##s, wih0, pre);                 \
        float e   = __builtin_amdgcn_exp2f(pre);                              \
        float act = fmaf(ascale, __builtin_amdgcn_rcpf(1.f + e), aoff);       \
        float ig  = act * dpp_qswap2(act);   /* q0 lane: i*g */               \
        float igb = dpp_q0(ig);                                               \
        float fv  = dpp_q1(act);                                              \
        float ov  = dpp_q3(act);                                              \
        c = fmaf(fv, c, igb);                                                 \
        float e2 = __builtin_amdgcn_exp2f(c);                                 \
        float th = fmaf(2.f, __builtin_amdgcn_rcpf(1.f + e2), -1.f);          \
        float h  = ov * th;                  /* quad-uniform */               \
        if (doStore) *op = h;                                                 \
        op += ostep;                                                          \
        hprev = h;                                                            \
    } while (0)

    for (int ch = 0; ch < NCH; ch++) {
        const bool last = (ch + 1 == NCH);
        float pf[NLD];
        if (!last) {   // issue next-chunk loads now; vmcnt-covered by CH steps
#pragma unroll
            for (int k = 0; k < NLD; k++) pf[k] = gnext[k * 64 + lane];
        }
        // steps 0 .. CH-3 (pairs), each prefetches its successor row
        for (int sl = 0; sl < CH - 2; sl += 2) {
            LSTM_STEP(xA, xB, true);
            LSTM_STEP(xB, xA, true);
        }
        LSTM_STEP(xA, xB, true);     // step CH-2 (prefetches row CH-1)
        LSTM_STEP(xB, xA, false);    // step CH-1 (no in-chunk prefetch)
        if (!last) {
            float* swn = xls + ((buf ^ 1) ? BUFSZ : 0);
#pragma unroll
            for (int k = 0; k < NLD; k++) swn[wdw[k]] = pf[k];
            buf ^= 1;
            lrow = swn;
            LOAD_ROW(xA, lrow);   // row 0 of new chunk
            gnext += gstep;
        }
    }
#undef LSTM_STEP
#undef LOAD_ROW
}

extern "C" void kernel_launch(void* const* d_in, const int* in_sizes, int n_in,
                              void* d_out, int out_size, void* d_ws, size_t ws_size,
                              hipStream_t stream) {
    const float* x        = (const float*)d_in[0]; // [2048,1,32,512]
    const float* W_ih0    = (const float*)d_in[1]; // [2,44,1]
    const float* W_ih_rest= (const float*)d_in[2]; // [4,2,44,22]
    const float* W_hh     = (const float*)d_in[3]; // [5,2,44,11]
    const float* b_ih     = (const float*)d_in[4]; // [5,2,44]
    const float* b_hh     = (const float*)d_in[5]; // [5,2,44]
    float* out = (float*)d_out;                    // [2048,512,22]

    // Workspace: one ping buffer of chunk*TT*22 floats; largest pow2 chunk
    // that fits ws_size. The x-reduction is staged in the same buffer (its
    // lifetime ends when layer 1 overwrites it). d_out is the pong buffer.
    const size_t perB = (size_t)TT * 22 * sizeof(float);
    int chunk = BB;
    while (chunk > 2 && (size_t)chunk * perB > ws_size) chunk >>= 1;
    float* wsbuf = (float*)d_ws;

    for (int c0 = 0; c0 < BB; c0 += chunk) {
        const float* xc   = x + (size_t)c0 * 32 * TT;
        float*       outc = out + (size_t)c0 * TT * 22;
        const int nblk = (chunk * 2) / 4;  // 4 sequences (waves) per block

        reduce_x<<<dim3(2, chunk), 256, 0, stream>>>(xc, wsbuf);

        lstm_layer<1><<<nblk, 256, 0, stream>>>(wsbuf, outc, W_ih0, W_hh, b_ih, b_hh);

        for (int l = 1; l < NL; l++) {
            const float* src = (l & 1) ? outc : wsbuf;
            float*       dst = (l & 1) ? wsbuf : outc;
            lstm_layer<22><<<nblk, 256, 0, stream>>>(
                src, dst,
                W_ih_rest + (size_t)(l - 1) * 2 * GG * 22,
                W_hh + (size_t)l * 2 * GG * HH,
                b_ih + (size_t)l * 2 * GG,
                b_hh + (size_t)l * 2 * GG);
        }
    }
}